// Round 6
// baseline (368.311 us; speedup 1.0000x reference)
//
#include <hip/hip_runtime.h>
#include <math.h>

#define B_ 2
#define T_ 2048
#define C_ 1024
#define H_ 16
#define HD_ 64
#define M_ (B_*T_)

typedef _Float16 half2v __attribute__((ext_vector_type(2)));
typedef _Float16 half4v __attribute__((ext_vector_type(4)));
typedef _Float16 half8v __attribute__((ext_vector_type(8)));
typedef float f32x4 __attribute__((ext_vector_type(4)));

#define GLD_LDS(gp, lp) \
  __builtin_amdgcn_global_load_lds( \
      (const __attribute__((address_space(1))) void*)(gp), \
      (__attribute__((address_space(3))) void*)(lp), 16, 0, 0)

// ---------------------------------------------------------------------------
// Elementwise fp32 -> f16 cast, float4-vectorized.
// ---------------------------------------------------------------------------
__global__ __launch_bounds__(256) void cast_f16_kernel(
    const float* __restrict__ src, _Float16* __restrict__ dst, int n4)
{
  int i = blockIdx.x * 256 + threadIdx.x;
  if (i < n4) {
    float4 v = ((const float4*)src)[i];
    half4v h; h[0] = (_Float16)v.x; h[1] = (_Float16)v.y;
    h[2] = (_Float16)v.z; h[3] = (_Float16)v.w;
    ((half4v*)dst)[i] = h;
  }
}

// ---------------------------------------------------------------------------
// All four W[K][N] fp32 -> Wt[n][k] f16 transposes in one launch (grid.z).
// ---------------------------------------------------------------------------
__global__ __launch_bounds__(256) void transpose_cast_all_kernel(
    const float* __restrict__ Wq, const float* __restrict__ Wk,
    const float* __restrict__ Wv, const float* __restrict__ Wo,
    _Float16* __restrict__ Wt3, _Float16* __restrict__ Wot)
{
  const float* W; _Float16* Wt;
  switch (blockIdx.z) {
    case 0:  W = Wq; Wt = Wt3; break;
    case 1:  W = Wk; Wt = Wt3 + (size_t)1024 * 1024; break;
    case 2:  W = Wv; Wt = Wt3 + (size_t)2048 * 1024; break;
    default: W = Wo; Wt = Wot; break;
  }
  __shared__ float tile[32][33];
  const int tx = threadIdx.x, ty = threadIdx.y;
  const int n0 = blockIdx.x * 32, k0 = blockIdx.y * 32;
#pragma unroll
  for (int r = 0; r < 4; r++) {
    int k = ty + r * 8;
    tile[k][tx] = W[(size_t)(k0 + k) * C_ + n0 + tx];
  }
  __syncthreads();
#pragma unroll
  for (int r = 0; r < 4; r++) {
    int n = ty + r * 8;
    Wt[(size_t)(n0 + n) * C_ + k0 + tx] = (_Float16)tile[tx][n];
  }
}

__global__ __launch_bounds__(256) void concat_bias_kernel(
    const float* __restrict__ bq, const float* __restrict__ bk,
    const float* __restrict__ bv, float* __restrict__ b3)
{
  int i = blockIdx.x * 256 + threadIdx.x;  // grid 12*256 = 3072
  const float* s = (i < 1024) ? bq : ((i < 2048) ? bk : bv);
  b3[i] = s[i & 1023];
}

// ---------------------------------------------------------------------------
// V [b,t,(h,d)] f16 -> Vt [(b,h,d), t] f16.  Grid (T/64, B*H), 256 threads.
// 64x64 tile via LDS; chunk-swizzled layout: element (d,t) lives at
// row d, col ((t>>3)^(d>>3))*8 + (t&7).  Phase-1 u16 writes conflict-free
// (banks 8*((row_t>>3)^cp)+(row_t&7) distinct per wave); phase-2 b128 reads
// 16B-aligned; global I/O 128B-contiguous per 8 lanes both directions.
// ---------------------------------------------------------------------------
__global__ __launch_bounds__(256) void transpose_v_kernel(
    const _Float16* __restrict__ Vh, _Float16* __restrict__ Vt)
{
  __shared__ __align__(16) _Float16 tile[64 * 64];
  const int tid = threadIdx.x;
  const int t0 = blockIdx.x * 64;
  const int bb = blockIdx.y >> 4, hh = blockIdx.y & 15;
#pragma unroll
  for (int i = 0; i < 2; i++) {
    int slot = tid + i * 256;            // 0..511
    int row_t = slot >> 3, cp = slot & 7;
    uint4 v = *(const uint4*)(Vh + (size_t)(bb * T_ + t0 + row_t) * C_ +
                              hh * 64 + cp * 8);
    half8v hv = __builtin_bit_cast(half8v, v);
    int c = ((row_t >> 3) ^ cp) * 8 + (row_t & 7);
#pragma unroll
    for (int j = 0; j < 8; j++)
      tile[(cp * 8 + j) * 64 + c] = hv[j];
  }
  __syncthreads();
#pragma unroll
  for (int i = 0; i < 2; i++) {
    int slot = tid + i * 256;            // 0..511
    int d_row = slot >> 3, tc = slot & 7;
    uint4 v = *(const uint4*)(tile + d_row * 64 + (tc ^ (d_row >> 3)) * 8);
    *(uint4*)(Vt + ((size_t)(bb * H_ + hh) * 64 + d_row) * 2048 + t0 + tc * 8) = v;
  }
}

// ---------------------------------------------------------------------------
// f16 MFMA GEMM: Out[M,N] = A[M,1024] @ Wt[N,1024]^T + bias.
// BK=32, 256 threads = 4 waves (2x2); wave tile (BM/2)x(BN/2).
// Staging via global_load_lds width=16 (m97 pattern).
// EPI 0: fused QKV epilogue (Q scaled by 0.125*log2e -> o0; K -> o1; V -> o2,
//        all plain [m][n] f16 stores).  EPI 1: fp32 out + bias (of).
// ---------------------------------------------------------------------------
template <int BM, int BN, int EPI>
__global__ __launch_bounds__(256) void gemm_f16_kernel(
    const _Float16* __restrict__ A, const _Float16* __restrict__ Bw,
    const float* __restrict__ bias,
    _Float16* __restrict__ o0, _Float16* __restrict__ o1,
    _Float16* __restrict__ o2, float* __restrict__ of)
{
  constexpr int FM = BM / 32, FN = BN / 32;
  __shared__ __align__(16) _Float16 As[BM * 32];
  __shared__ __align__(16) _Float16 Bs[BN * 32];
  const int t = threadIdx.x;
  const int w = t >> 6, lane = t & 63, l15 = lane & 15, quad = lane >> 4;
  const int wm = (w & 1) * (BM / 2), wn = (w >> 1) * (BN / 2);
  const int bm = blockIdx.y * BM, bn = blockIdx.x * BN;
  const int lrow = lane >> 2, lcol = (lane & 3) * 8;  // staging: 16 rows/call

  f32x4 acc[FM][FN];
#pragma unroll
  for (int i = 0; i < FM; i++)
#pragma unroll
    for (int j = 0; j < FN; j++) acc[i][j] = (f32x4){0.f, 0.f, 0.f, 0.f};

  for (int k0 = 0; k0 < 1024; k0 += 32) {
#pragma unroll
    for (int i = 0; i < BM / 64; i++) {
      int ca = w + 4 * i;
      int row = ca * 16 + lrow;
      GLD_LDS(A + (size_t)(bm + row) * 1024 + k0 + lcol, As + ca * 512);
    }
#pragma unroll
    for (int i = 0; i < BN / 64; i++) {
      int cb = w + 4 * i;
      int row = cb * 16 + lrow;
      GLD_LDS(Bw + (size_t)(bn + row) * 1024 + k0 + lcol, Bs + cb * 512);
    }
    __syncthreads();

    half8v af[FM], bf[FN];
#pragma unroll
    for (int mt = 0; mt < FM; mt++)
      af[mt] = *(const half8v*)(As + (wm + mt * 16 + l15) * 32 + quad * 8);
#pragma unroll
    for (int nt = 0; nt < FN; nt++)
      bf[nt] = *(const half8v*)(Bs + (wn + nt * 16 + l15) * 32 + quad * 8);
#pragma unroll
    for (int mt = 0; mt < FM; mt++)
#pragma unroll
      for (int nt = 0; nt < FN; nt++)
        acc[mt][nt] = __builtin_amdgcn_mfma_f32_16x16x32_f16(
            af[mt], bf[nt], acc[mt][nt], 0, 0, 0);
    __syncthreads();
  }

  // Epilogue. C/D layout: col = l15 (n), row = quad*4 + r (m).
#pragma unroll
  for (int mt = 0; mt < FM; mt++)
#pragma unroll
    for (int nt = 0; nt < FN; nt++) {
      int n = bn + wn + nt * 16 + l15;
      float bv = bias[n];
#pragma unroll
      for (int r = 0; r < 4; r++) {
        int m = bm + wm + mt * 16 + quad * 4 + r;
        float v = acc[mt][nt][r] + bv;
        if (EPI == 0) {
          if (bn < 1024) {
            // Q pre-scaled by 0.125 * log2(e) for base-2 softmax.
            o0[(size_t)m * 1024 + n] = (_Float16)(v * 0.180336884f);
          } else if (bn < 2048) {
            o1[(size_t)m * 1024 + (n - 1024)] = (_Float16)v;    // K
          } else {
            o2[(size_t)m * 1024 + (n - 2048)] = (_Float16)v;    // V (plain)
          }
        } else {
          of[(size_t)m * 1024 + n] = v;
        }
      }
    }
}

// ---------------------------------------------------------------------------
// MFMA flash attention (no mask, per reference). Grid (T/64, H, B), 256 thr.
// Wave w owns 16 query columns q = qt*64 + w*16 + l15.
// S^T = K·Q^T via 16x16x32_f16 (C-layout row=key, col=q); P lands exactly in
// the 16x16x16f16 B-operand layout -> PV with zero LDS round-trip.
// LDS rows padded to 136 B -> conflict-free.  Softmax base-2.
// V6: double-buffered K/V LDS + register prefetch of tile t+1 before compute
// of tile t; ONE barrier per tile (writes go to the other buffer, so the
// barrier at tile end orders them against all waves' reads).  Wave-uniform
// skip of the alpha-rescale when no lane's running max changed (__any).
// ---------------------------------------------------------------------------
__global__ __launch_bounds__(256) void attn_f16_kernel(
    const _Float16* __restrict__ Qh, const _Float16* __restrict__ Kh,
    const _Float16* __restrict__ Vt, _Float16* __restrict__ Yh)
{
  __shared__ __align__(16) _Float16 Ks[2 * 64 * 68];
  __shared__ __align__(16) _Float16 Vs[2 * 64 * 68];
  const int t = threadIdx.x;
  const int w = t >> 6, lane = t & 63, l15 = lane & 15, quad = lane >> 4;
  const int qt = blockIdx.x, h = blockIdx.y, b = blockIdx.z;
  const int qg = qt * 64 + w * 16 + l15;
  const size_t qoff = ((size_t)(b * T_ + qg)) * C_ + h * HD_;

  half8v qf[2];
  qf[0] = *(const half8v*)(Qh + qoff + quad * 8);
  qf[1] = *(const half8v*)(Qh + qoff + 32 + quad * 8);

  f32x4 o[4];
#pragma unroll
  for (int i = 0; i < 4; i++) o[i] = (f32x4){0.f, 0.f, 0.f, 0.f};
  float m_run = -INFINITY, l_run = 0.f;

  const size_t kbase = ((size_t)b * T_) * C_ + h * HD_;
  const size_t vbase = ((size_t)(b * H_ + h)) * HD_ * 2048;

  const int srow = t >> 3, scp = t & 7;  // staging: 8x16B chunks per row

  // Preload tile 0 into buffer 0.
  uint4 pk[2], pv[2];
#pragma unroll
  for (int i = 0; i < 2; i++) {
    int row = srow + i * 32;
    pk[i] = *(const uint4*)(Kh + kbase + (size_t)row * C_ + scp * 8);
    pv[i] = *(const uint4*)(Vt + vbase + (size_t)row * 2048 + scp * 8);
  }
#pragma unroll
  for (int i = 0; i < 2; i++) {
    int row = srow + i * 32;
    *(uint4*)((char*)Ks + row * 136 + scp * 16) = pk[i];
    *(uint4*)((char*)Vs + row * 136 + scp * 16) = pv[i];
  }
  __syncthreads();

  for (int kt0 = 0; kt0 < T_; kt0 += 64) {
    const int cur = (kt0 >> 6) & 1;
    const char* Ksc = (const char*)(Ks + cur * (64 * 68));
    const char* Vsc = (const char*)(Vs + cur * (64 * 68));
    const bool more = (kt0 + 64) < T_;

    // Prefetch next tile into registers (hidden behind this tile's compute).
    if (more) {
      int kn = kt0 + 64;
#pragma unroll
      for (int i = 0; i < 2; i++) {
        int row = srow + i * 32;
        pk[i] = *(const uint4*)(Kh + kbase + (size_t)(kn + row) * C_ + scp * 8);
        pv[i] = *(const uint4*)(Vt + vbase + (size_t)row * 2048 + kn + scp * 8);
      }
    }

    // S^T tiles: 4 key-tiles x 2 d-steps of 16x16x32.
    f32x4 s[4];
#pragma unroll
    for (int kt = 0; kt < 4; kt++) {
      s[kt] = (f32x4){0.f, 0.f, 0.f, 0.f};
      int key = kt * 16 + l15;
#pragma unroll
      for (int ks = 0; ks < 2; ks++) {
        half8v kf = *(const half8v*)(Ksc + key * 136 + (ks * 4 + quad) * 16);
        s[kt] = __builtin_amdgcn_mfma_f32_16x16x32_f16(kf, qf[ks], s[kt], 0, 0, 0);
      }
    }

    // Online softmax (base-2), per q column = l15.
    float tmax = -INFINITY;
#pragma unroll
    for (int kt = 0; kt < 4; kt++)
#pragma unroll
      for (int r = 0; r < 4; r++) tmax = fmaxf(tmax, s[kt][r]);
    tmax = fmaxf(tmax, __shfl_xor(tmax, 16));
    tmax = fmaxf(tmax, __shfl_xor(tmax, 32));
    if (__any(tmax > m_run)) {
      float mnew = fmaxf(m_run, tmax);
      float alpha = __builtin_amdgcn_exp2f(m_run - mnew);
      l_run *= alpha;
#pragma unroll
      for (int dt = 0; dt < 4; dt++) o[dt] *= alpha;
      m_run = mnew;
    }

    float psum = 0.f;
    half4v pf[4];
#pragma unroll
    for (int kt = 0; kt < 4; kt++) {
      float p0 = __builtin_amdgcn_exp2f(s[kt][0] - m_run);
      float p1 = __builtin_amdgcn_exp2f(s[kt][1] - m_run);
      float p2 = __builtin_amdgcn_exp2f(s[kt][2] - m_run);
      float p3 = __builtin_amdgcn_exp2f(s[kt][3] - m_run);
      psum += (p0 + p1) + (p2 + p3);
      half2v pk01 = __builtin_bit_cast(half2v, __builtin_amdgcn_cvt_pkrtz(p0, p1));
      half2v pk23 = __builtin_bit_cast(half2v, __builtin_amdgcn_cvt_pkrtz(p2, p3));
      pf[kt] = __builtin_shufflevector(pk01, pk23, 0, 1, 2, 3);
    }
    psum += __shfl_xor(psum, 16);
    psum += __shfl_xor(psum, 32);
    l_run += psum;

    // PV: o^T[d][q] += V^T x P, 4 d-tiles x 4 key-tiles of 16x16x16.
#pragma unroll
    for (int dt = 0; dt < 4; dt++) {
      int d = dt * 16 + l15;
#pragma unroll
      for (int kt = 0; kt < 4; kt++) {
        half4v vf = *(const half4v*)(Vsc + d * 136 + kt * 32 + quad * 8);
        o[dt] = __builtin_amdgcn_mfma_f32_16x16x16f16(vf, pf[kt], o[dt], 0, 0, 0);
      }
    }

    // Stage prefetched tile into the other buffer; single barrier.
    if (more) {
      char* Ksn = (char*)(Ks + (cur ^ 1) * (64 * 68));
      char* Vsn = (char*)(Vs + (cur ^ 1) * (64 * 68));
#pragma unroll
      for (int i = 0; i < 2; i++) {
        int row = srow + i * 32;
        *(uint4*)(Ksn + row * 136 + scp * 16) = pk[i];
        *(uint4*)(Vsn + row * 136 + scp * 16) = pv[i];
      }
    }
    __syncthreads();
  }

  float inv = 1.0f / l_run;
#pragma unroll
  for (int dt = 0; dt < 4; dt++) {
    half4v yv;
#pragma unroll
    for (int r = 0; r < 4; r++) yv[r] = (_Float16)(o[dt][r] * inv);
    *(half4v*)(Yh + qoff + dt * 16 + quad * 4) = yv;  // row q, cols h*64+d..
  }
}

// ---------------------------------------------------------------------------
extern "C" void kernel_launch(void* const* d_in, const int* in_sizes, int n_in,
                              void* d_out, int out_size, void* d_ws, size_t ws_size,
                              hipStream_t stream) {
  const float* x  = (const float*)d_in[0];
  const float* Wq = (const float*)d_in[1];
  const float* bq = (const float*)d_in[2];
  const float* Wk = (const float*)d_in[3];
  const float* bk = (const float*)d_in[4];
  const float* Wv = (const float*)d_in[5];
  const float* bv = (const float*)d_in[6];
  const float* Wo = (const float*)d_in[7];
  const float* bo = (const float*)d_in[8];
  float* out = (float*)d_out;

  // Workspace carve-up (bytes). Each f16 plane M_*C_ = 8 MB.
  char* ws = (char*)d_ws;
  _Float16* xh   = (_Float16*)(ws);                        // 8 MB
  _Float16* Qh   = (_Float16*)(ws + (((size_t)8)  << 20)); // 8 MB
  _Float16* Kh   = (_Float16*)(ws + (((size_t)16) << 20)); // 8 MB
  _Float16* Vh   = (_Float16*)(ws + (((size_t)24) << 20)); // 8 MB  [b,t,h*64+d]
  _Float16* Vt   = (_Float16*)(ws + (((size_t)32) << 20)); // 8 MB  [b,h,d,t]
  _Float16* Yh   = (_Float16*)(ws + (((size_t)40) << 20)); // 8 MB
  _Float16* Wt3  = (_Float16*)(ws + (((size_t)48) << 20)); // 6 MB  [3072][1024]
  _Float16* Wot  = (_Float16*)(ws + (((size_t)54) << 20)); // 2 MB  [1024][1024]
  float*    b3   = (float*)   (ws + (((size_t)56) << 20)); // 12 KB

  cast_f16_kernel<<<(M_ * C_ / 4 + 255) / 256, 256, 0, stream>>>(x, xh, M_ * C_ / 4);
  transpose_cast_all_kernel<<<dim3(32, 32, 4), dim3(32, 8), 0, stream>>>(
      Wq, Wk, Wv, Wo, Wt3, Wot);
  concat_bias_kernel<<<12, 256, 0, stream>>>(bq, bk, bv, b3);

  // Fused QKV projection: [4096,1024] @ [1024,3072] -> Q,K,V (f16).
  gemm_f16_kernel<128, 128, 0><<<dim3(24, 32), 256, 0, stream>>>(
      xh, Wt3, b3, Qh, Kh, Vh, nullptr);

  transpose_v_kernel<<<dim3(T_ / 64, B_ * H_), 256, 0, stream>>>(Vh, Vt);

  attn_f16_kernel<<<dim3(T_ / 64, H_, B_), 256, 0, stream>>>(Qh, Kh, Vt, Yh);

  // Output projection: Yh @ Wot^T + bo -> fp32 out.
  gemm_f16_kernel<64, 128, 1><<<dim3(8, 64), 256, 0, stream>>>(
      Yh, Wot, bo, nullptr, nullptr, nullptr, out);
}

// Round 7
// 323.667 us; speedup vs baseline: 1.1379x; 1.1379x over previous
//
#include <hip/hip_runtime.h>
#include <math.h>

#define B_ 2
#define T_ 2048
#define C_ 1024
#define H_ 16
#define HD_ 64
#define M_ (B_*T_)

typedef _Float16 half2v __attribute__((ext_vector_type(2)));
typedef _Float16 half4v __attribute__((ext_vector_type(4)));
typedef _Float16 half8v __attribute__((ext_vector_type(8)));
typedef float f32x4 __attribute__((ext_vector_type(4)));

#define GLD_LDS(gp, lp) \
  __builtin_amdgcn_global_load_lds( \
      (const __attribute__((address_space(1))) void*)(gp), \
      (__attribute__((address_space(3))) void*)(lp), 16, 0, 0)

// ---------------------------------------------------------------------------
// Fused prep: fp32->f16 cast of x (blocks 0..4095), 4 weight transposes
// (blocks 4096..8191), bias concat (blocks 8192..8203). One launch.
// ---------------------------------------------------------------------------
__global__ __launch_bounds__(256) void prep_kernel(
    const float* __restrict__ x,
    const float* __restrict__ Wq, const float* __restrict__ Wk,
    const float* __restrict__ Wv, const float* __restrict__ Wo,
    const float* __restrict__ bq, const float* __restrict__ bk,
    const float* __restrict__ bv,
    _Float16* __restrict__ xh, _Float16* __restrict__ Wt3,
    _Float16* __restrict__ Wot, float* __restrict__ b3)
{
  __shared__ float tile[32][33];
  const int blk = blockIdx.x, thr = threadIdx.x;
  if (blk < 4096) {
    // cast x: 4096 blocks x 256 float4 = all of M_*C_.
    int i = blk * 256 + thr;
    float4 v = ((const float4*)x)[i];
    half4v h; h[0] = (_Float16)v.x; h[1] = (_Float16)v.y;
    h[2] = (_Float16)v.z; h[3] = (_Float16)v.w;
    ((half4v*)xh)[i] = h;
  } else if (blk < 8192) {
    int zz = (blk - 4096) >> 10;      // which W
    int bxy = (blk - 4096) & 1023;
    const float* W; _Float16* Wt;
    switch (zz) {
      case 0:  W = Wq; Wt = Wt3; break;
      case 1:  W = Wk; Wt = Wt3 + (size_t)1024 * 1024; break;
      case 2:  W = Wv; Wt = Wt3 + (size_t)2048 * 1024; break;
      default: W = Wo; Wt = Wot; break;
    }
    const int n0 = (bxy & 31) * 32, k0 = (bxy >> 5) * 32;
    const int tx = thr & 31, ty = thr >> 5;  // 32 x 8
#pragma unroll
    for (int r = 0; r < 4; r++) {
      int k = ty + r * 8;
      tile[k][tx] = W[(size_t)(k0 + k) * C_ + n0 + tx];
    }
    __syncthreads();
#pragma unroll
    for (int r = 0; r < 4; r++) {
      int n = ty + r * 8;
      Wt[(size_t)(n0 + n) * C_ + k0 + tx] = (_Float16)tile[tx][n];
    }
  } else {
    int i = (blk - 8192) * 256 + thr;  // 0..3071
    const float* s = (i < 1024) ? bq : ((i < 2048) ? bk : bv);
    b3[i] = s[i & 1023];
  }
}

// ---------------------------------------------------------------------------
// f16 MFMA GEMM: Out[M,N] = A[M,1024] @ Wt[N,1024]^T + bias.
// BK=32, 256 threads = 4 waves (2x2); wave tile (BM/2)x(BN/2).
// Staging via global_load_lds width=16 (m97 pattern).
// EPI 0: fused QKV epilogue (Q scaled by 0.125*log2e -> o0; K -> o1;
//        V transposed -> o2 as [b,h,d,t]; scatter absorbed by L2).
// EPI 1: fp32 out + bias (of).
// ---------------------------------------------------------------------------
template <int BM, int BN, int EPI>
__global__ __launch_bounds__(256) void gemm_f16_kernel(
    const _Float16* __restrict__ A, const _Float16* __restrict__ Bw,
    const float* __restrict__ bias,
    _Float16* __restrict__ o0, _Float16* __restrict__ o1,
    _Float16* __restrict__ o2, float* __restrict__ of)
{
  constexpr int FM = BM / 32, FN = BN / 32;
  __shared__ __align__(16) _Float16 As[BM * 32];
  __shared__ __align__(16) _Float16 Bs[BN * 32];
  const int t = threadIdx.x;
  const int w = t >> 6, lane = t & 63, l15 = lane & 15, quad = lane >> 4;
  const int wm = (w & 1) * (BM / 2), wn = (w >> 1) * (BN / 2);
  const int bm = blockIdx.y * BM, bn = blockIdx.x * BN;
  const int lrow = lane >> 2, lcol = (lane & 3) * 8;  // staging: 16 rows/call

  f32x4 acc[FM][FN];
#pragma unroll
  for (int i = 0; i < FM; i++)
#pragma unroll
    for (int j = 0; j < FN; j++) acc[i][j] = (f32x4){0.f, 0.f, 0.f, 0.f};

  for (int k0 = 0; k0 < 1024; k0 += 32) {
#pragma unroll
    for (int i = 0; i < BM / 64; i++) {
      int ca = w + 4 * i;
      int row = ca * 16 + lrow;
      GLD_LDS(A + (size_t)(bm + row) * 1024 + k0 + lcol, As + ca * 512);
    }
#pragma unroll
    for (int i = 0; i < BN / 64; i++) {
      int cb = w + 4 * i;
      int row = cb * 16 + lrow;
      GLD_LDS(Bw + (size_t)(bn + row) * 1024 + k0 + lcol, Bs + cb * 512);
    }
    __syncthreads();

    half8v af[FM], bf[FN];
#pragma unroll
    for (int mt = 0; mt < FM; mt++)
      af[mt] = *(const half8v*)(As + (wm + mt * 16 + l15) * 32 + quad * 8);
#pragma unroll
    for (int nt = 0; nt < FN; nt++)
      bf[nt] = *(const half8v*)(Bs + (wn + nt * 16 + l15) * 32 + quad * 8);
#pragma unroll
    for (int mt = 0; mt < FM; mt++)
#pragma unroll
      for (int nt = 0; nt < FN; nt++)
        acc[mt][nt] = __builtin_amdgcn_mfma_f32_16x16x32_f16(
            af[mt], bf[nt], acc[mt][nt], 0, 0, 0);
    __syncthreads();
  }

  // Epilogue. C/D layout: col = l15 (n), row = quad*4 + r (m).
#pragma unroll
  for (int mt = 0; mt < FM; mt++)
#pragma unroll
    for (int nt = 0; nt < FN; nt++) {
      int n = bn + wn + nt * 16 + l15;
      float bv = bias[n];
#pragma unroll
      for (int r = 0; r < 4; r++) {
        int m = bm + wm + mt * 16 + quad * 4 + r;
        float v = acc[mt][nt][r] + bv;
        if (EPI == 0) {
          if (bn < 1024) {
            // Q pre-scaled by 0.125 * log2(e) for base-2 softmax.
            o0[(size_t)m * 1024 + n] = (_Float16)(v * 0.180336884f);
          } else if (bn < 2048) {
            o1[(size_t)m * 1024 + (n - 1024)] = (_Float16)v;    // K
          } else {
            int dg = n - 2048;
            int hh = dg >> 6, hd = dg & 63;
            int bb = m >> 11, tt = m & 2047;
            o2[(((size_t)(bb * H_ + hh)) * 64 + hd) * 2048 + tt] = (_Float16)v;  // V^T
          }
        } else {
          of[(size_t)m * 1024 + n] = v;
        }
      }
    }
}

// ---------------------------------------------------------------------------
// MFMA flash attention (no mask, per reference). Grid (T/64, H, B), 256 thr.
// Wave w owns 16 query columns q = qt*64 + w*16 + l15.
// S^T = K·Q^T via 16x16x32_f16 (C-layout row=key, col=q); P lands exactly in
// the 16x16x16f16 B-operand layout -> PV with zero LDS round-trip.
// LDS rows padded to 136 B -> conflict-free.  Softmax base-2.
// V7: double-buffered LDS, ONE barrier per tile, staging regs SHORT-LIVED
// (load -> LDS write -> barrier, all before compute; v6's long-lived register
// prefetch spilled to scratch: WRITE_SIZE 8MB->350MB).  Safety: a wave
// writing buf(t+1) passed barrier(t), which requires all waves finished
// compute(t-1) - the only readers of buf(t+1)=buf(t-1).
// ---------------------------------------------------------------------------
__global__ __launch_bounds__(256) void attn_f16_kernel(
    const _Float16* __restrict__ Qh, const _Float16* __restrict__ Kh,
    const _Float16* __restrict__ Vt, _Float16* __restrict__ Yh)
{
  __shared__ __align__(16) _Float16 Ks[2 * 64 * 68];
  __shared__ __align__(16) _Float16 Vs[2 * 64 * 68];
  const int t = threadIdx.x;
  const int w = t >> 6, lane = t & 63, l15 = lane & 15, quad = lane >> 4;
  const int qt = blockIdx.x, h = blockIdx.y, b = blockIdx.z;
  const int qg = qt * 64 + w * 16 + l15;
  const size_t qoff = ((size_t)(b * T_ + qg)) * C_ + h * HD_;

  half8v qf[2];
  qf[0] = *(const half8v*)(Qh + qoff + quad * 8);
  qf[1] = *(const half8v*)(Qh + qoff + 32 + quad * 8);

  f32x4 o[4];
#pragma unroll
  for (int i = 0; i < 4; i++) o[i] = (f32x4){0.f, 0.f, 0.f, 0.f};
  float m_run = -INFINITY, l_run = 0.f;

  const size_t kbase = ((size_t)b * T_) * C_ + h * HD_;
  const size_t vbase = ((size_t)(b * H_ + h)) * HD_ * 2048;

  const int srow = t >> 3, scp = t & 7;  // staging: 8x16B chunks per row

  for (int kt0 = 0; kt0 < T_; kt0 += 64) {
    const int cur = (kt0 >> 6) & 1;
    char* Ksc = (char*)(Ks + cur * (64 * 68));
    char* Vsc = (char*)(Vs + cur * (64 * 68));

    // Stage this tile: global -> VGPR -> LDS[cur]; regs die at the barrier.
    {
      uint4 k0v = *(const uint4*)(Kh + kbase + (size_t)(kt0 + srow) * C_ + scp * 8);
      uint4 k1v = *(const uint4*)(Kh + kbase + (size_t)(kt0 + srow + 32) * C_ + scp * 8);
      uint4 v0v = *(const uint4*)(Vt + vbase + (size_t)srow * 2048 + kt0 + scp * 8);
      uint4 v1v = *(const uint4*)(Vt + vbase + (size_t)(srow + 32) * 2048 + kt0 + scp * 8);
      *(uint4*)(Ksc + srow * 136 + scp * 16) = k0v;
      *(uint4*)(Ksc + (srow + 32) * 136 + scp * 16) = k1v;
      *(uint4*)(Vsc + srow * 136 + scp * 16) = v0v;
      *(uint4*)(Vsc + (srow + 32) * 136 + scp * 16) = v1v;
    }
    __syncthreads();

    // S^T tiles: 4 key-tiles x 2 d-steps of 16x16x32.
    f32x4 s[4];
#pragma unroll
    for (int kt = 0; kt < 4; kt++) {
      s[kt] = (f32x4){0.f, 0.f, 0.f, 0.f};
      int key = kt * 16 + l15;
#pragma unroll
      for (int ks = 0; ks < 2; ks++) {
        half8v kf = *(const half8v*)(Ksc + key * 136 + (ks * 4 + quad) * 16);
        s[kt] = __builtin_amdgcn_mfma_f32_16x16x32_f16(kf, qf[ks], s[kt], 0, 0, 0);
      }
    }

    // Online softmax (base-2), per q column = l15.
    float tmax = -INFINITY;
#pragma unroll
    for (int kt = 0; kt < 4; kt++)
#pragma unroll
      for (int r = 0; r < 4; r++) tmax = fmaxf(tmax, s[kt][r]);
    tmax = fmaxf(tmax, __shfl_xor(tmax, 16));
    tmax = fmaxf(tmax, __shfl_xor(tmax, 32));
    if (__any(tmax > m_run)) {
      float mnew = fmaxf(m_run, tmax);
      float alpha = __builtin_amdgcn_exp2f(m_run - mnew);
      l_run *= alpha;
#pragma unroll
      for (int dt = 0; dt < 4; dt++) o[dt] *= alpha;
      m_run = mnew;
    }

    float psum = 0.f;
    half4v pf[4];
#pragma unroll
    for (int kt = 0; kt < 4; kt++) {
      float p0 = __builtin_amdgcn_exp2f(s[kt][0] - m_run);
      float p1 = __builtin_amdgcn_exp2f(s[kt][1] - m_run);
      float p2 = __builtin_amdgcn_exp2f(s[kt][2] - m_run);
      float p3 = __builtin_amdgcn_exp2f(s[kt][3] - m_run);
      psum += (p0 + p1) + (p2 + p3);
      half2v pk01 = __builtin_bit_cast(half2v, __builtin_amdgcn_cvt_pkrtz(p0, p1));
      half2v pk23 = __builtin_bit_cast(half2v, __builtin_amdgcn_cvt_pkrtz(p2, p3));
      pf[kt] = __builtin_shufflevector(pk01, pk23, 0, 1, 2, 3);
    }
    psum += __shfl_xor(psum, 16);
    psum += __shfl_xor(psum, 32);
    l_run += psum;

    // PV: o^T[d][q] += V^T x P, 4 d-tiles x 4 key-tiles of 16x16x16.
#pragma unroll
    for (int dt = 0; dt < 4; dt++) {
      int d = dt * 16 + l15;
#pragma unroll
      for (int kt = 0; kt < 4; kt++) {
        half4v vf = *(const half4v*)(Vsc + d * 136 + kt * 32 + quad * 8);
        o[dt] = __builtin_amdgcn_mfma_f32_16x16x16f16(vf, pf[kt], o[dt], 0, 0, 0);
      }
    }
    // No trailing barrier: next iteration writes the other buffer.
  }

  float inv = 1.0f / l_run;
#pragma unroll
  for (int dt = 0; dt < 4; dt++) {
    half4v yv;
#pragma unroll
    for (int r = 0; r < 4; r++) yv[r] = (_Float16)(o[dt][r] * inv);
    *(half4v*)(Yh + qoff + dt * 16 + quad * 4) = yv;  // row q, cols h*64+d..
  }
}

// ---------------------------------------------------------------------------
extern "C" void kernel_launch(void* const* d_in, const int* in_sizes, int n_in,
                              void* d_out, int out_size, void* d_ws, size_t ws_size,
                              hipStream_t stream) {
  const float* x  = (const float*)d_in[0];
  const float* Wq = (const float*)d_in[1];
  const float* bq = (const float*)d_in[2];
  const float* Wk = (const float*)d_in[3];
  const float* bk = (const float*)d_in[4];
  const float* Wv = (const float*)d_in[5];
  const float* bv = (const float*)d_in[6];
  const float* Wo = (const float*)d_in[7];
  const float* bo = (const float*)d_in[8];
  float* out = (float*)d_out;

  // Workspace carve-up (bytes). Each f16 plane M_*C_ = 8 MB.
  char* ws = (char*)d_ws;
  _Float16* xh   = (_Float16*)(ws);                        // 8 MB
  _Float16* Qh   = (_Float16*)(ws + (((size_t)8)  << 20)); // 8 MB
  _Float16* Kh   = (_Float16*)(ws + (((size_t)16) << 20)); // 8 MB
  _Float16* Vt   = (_Float16*)(ws + (((size_t)24) << 20)); // 8 MB  [b,h,d,t]
  _Float16* Yh   = (_Float16*)(ws + (((size_t)32) << 20)); // 8 MB
  _Float16* Wt3  = (_Float16*)(ws + (((size_t)40) << 20)); // 6 MB  [3072][1024]
  _Float16* Wot  = (_Float16*)(ws + (((size_t)46) << 20)); // 2 MB  [1024][1024]
  float*    b3   = (float*)   (ws + (((size_t)48) << 20)); // 12 KB

  prep_kernel<<<8204, 256, 0, stream>>>(x, Wq, Wk, Wv, Wo, bq, bk, bv,
                                        xh, Wt3, Wot, b3);

  // Fused QKV projection: [4096,1024] @ [1024,3072] -> Q,K (f16) + V^T (f16).
  gemm_f16_kernel<128, 128, 0><<<dim3(24, 32), 256, 0, stream>>>(
      xh, Wt3, b3, Qh, Kh, Vt, nullptr);

  attn_f16_kernel<<<dim3(T_ / 64, H_, B_), 256, 0, stream>>>(Qh, Kh, Vt, Yh);

  // Output projection: Yh @ Wot^T + bo -> fp32 out.
  gemm_f16_kernel<64, 128, 1><<<dim3(8, 64), 256, 0, stream>>>(
      Yh, Wot, bo, nullptr, nullptr, nullptr, out);
}